// Round 18
// baseline (5075.706 us; speedup 1.0000x reference)
//
#include <hip/hip_runtime.h>
#include <math.h>

// TD3ActorDSNN — f32 class-faithful, fused, round 18.
// Exactness invariants (validated r4-r6, r9, r11-r17):
//  - per-element k-ascending single-accumulator f32 chains for h0 and h1;
//    skipping k with mask==0 is bit-identical; per-chain k-order fixed.
//  - b in {0,1}: fma(b,w,acc) EXACT (b=1 -> RN(acc+w) == validated add;
//    b=0 -> acc unchanged; acc never -0 in a +0-seeded add chain).
//  - masks periodic (mem0 resets to exact 0): n = ctz+1; bit t = ((t+1)%n==0).
//  - recurrences: __fadd_rn(__fmul_rn(beta,state),h) (np mul-then-add).
//  - layer2/mem2: order-free (tanh input, tol 2e-2 >> 1e-6 noise).
// Codegen ledger:
//  SPILL: any branch/asm on the 60 live accs (r7/r8/r13/r15); launch_bounds
//    (,8) VGPR cap (r10). SAFE: single-BB portable body at (256,4).
//  r14: DENSE per-t SALU selects (30/entry) saturate the CU-shared scalar
//    pipe; sparse scalar work (~6/entry) is fine.
//  r16: b from LUT loads -> 83 VALU/entry, 2.65ms best.
//  r17 + spec: v_pk_fma_f32 has NO rate advantage on gfx950 (157.3 TF peak
//    == scalar SIMD-32 fma rate; CDNA3's dual-pump is gone). Floor = 60
//    scalar v_fmac/entry. The lever is killing the ~23 overhead VALU ops.
// Round-18: uniformity-driven scalarization of ALL overhead (HK tech #5):
//  readfirstlane'd pointers -> list via s_load_dwordx4 (4 entries/op),
//  b-row via s_load_dwordx16 -> SGPRs feed v_fmac src0 (zero VALU),
//  w addr = SGPR base (scalar chain) + loop-invariant lane voffset.
//  List entry = k<<13 | n (pre-scaled byte offset).

typedef unsigned int u32;
typedef unsigned short u16;
typedef unsigned long long u64;

// ---- K1: h0 = inputs @ W0 (f32 fma chain) + fused mem0 recurrence -> s0bR ----
__global__ __launch_bounds__(256) void h0_kernel(
    const float* __restrict__ in, const float* __restrict__ W0,
    u16* __restrict__ s0bR) {
    __shared__ float Ls[32 * 512];
    int tid = threadIdx.x;
    int j = blockIdx.x * 256 + tid;
    int r0 = blockIdx.y * 32;
#pragma unroll
    for (int i = 0; i < 64; ++i) {
        int e = i * 256 + tid;
        Ls[e] = in[(size_t)(r0 + (e >> 9)) * 512 + (e & 511)];
    }
    __syncthreads();
    float acc[32];
#pragma unroll
    for (int r = 0; r < 32; ++r) acc[r] = 0.f;
    for (int k = 0; k < 512; ++k) {
        float w = W0[(size_t)k * 2048 + j];
#pragma unroll
        for (int r = 0; r < 32; ++r)
            acc[r] = __fmaf_rn(Ls[r * 512 + k], w, acc[r]);
    }
#pragma unroll
    for (int r = 0; r < 32; ++r) {
        float h = acc[r], mem = 0.f;
        u32 bits = 0;
#pragma unroll
        for (int t = 0; t < 15; ++t) {
            float nm = __fadd_rn(__fmul_rn(0.85f, mem), h);  // np: mul, then add
            bool sp = nm > 1.0f;
            bits |= (sp ? 1u : 0u) << t;
            mem = sp ? 0.f : nm;
        }
        s0bR[(size_t)(r0 + r) * 2048 + j] = (u16)bits;
    }
}

// ---- K1b: active-k compaction (k-ascending) + 16x16 b-LUT ----
// entry = k<<13 | n  (k<<13 = byte offset of W1 row; n = ctz(mask)+1).
// padded to multiple of 4 with 0 (n=0 -> lut row 0 zeros -> exact no-op).
__global__ __launch_bounds__(256) void compact_kernel(
    const u16* __restrict__ s0bR, u32* __restrict__ list,
    int* __restrict__ ccnt, float* __restrict__ lut) {
    int wv = threadIdx.x >> 6, lane = threadIdx.x & 63;
    if (blockIdx.x == 0) {    // lut[n][t] = ((t+1)%n==0), row 0 = zeros
        int n = threadIdx.x >> 4, t = threadIdx.x & 15;
        lut[threadIdx.x] = (n >= 1 && t < 15 && ((t + 1) % n == 0)) ? 1.0f : 0.0f;
    }
    int row = blockIdx.x * 4 + wv;
    const u16* mrow = s0bR + (size_t)row * 2048;
    u32* lrow = list + (size_t)row * 2048;
    int base = 0;
    for (int c = 0; c < 32; ++c) {
        int k = c * 64 + lane;
        u32 m = mrow[k];
        bool act = m != 0u;
        u64 b = __ballot(act ? 1 : 0);
        int pre = __popcll(b & ((1ull << lane) - 1ull));
        if (act) lrow[base + pre] =
            ((u32)k << 13) | (u32)(__builtin_ctz(m | 0x10000u) + 1);
        base += __popcll(b);
    }
    int padded = (base + 3) & ~3;
    if (lane < (padded - base)) lrow[base + lane] = 0u;
    if (lane == 0) ccnt[row] = padded;
}

// ---- K2: FUSED h1 (15 steps) over ACTIVE k only + recurrence -> s1b ----
// Wave: 1 row x 256 cols (lane: 4 cols). Block: 4 rows. grid 8192:
// jb = id&7 (XCD-affine W1 slice), rblk = id>>3.
// All overhead scalar: s_load list (4 entries/op), s_load b-row (SGPR ->
// v_fmac src0), SGPR w-base + loop-invariant lane voffset.
__global__ __launch_bounds__(256, 4) void h1_fused14(
    const float* __restrict__ W1, const u32* __restrict__ list,
    const int* __restrict__ ccnt, const float* __restrict__ lut,
    u16* __restrict__ s1b) {
    int id = blockIdx.x;
    int jb = id & 7, rblk = id >> 3;
    int lane = threadIdx.x & 63, wv = threadIdx.x >> 6;
    int row = rblk * 4 + wv;
    int j0 = jb * 256 + lane * 4;

    // wave-uniform (SGPR) pointers via readfirstlane — divergence analysis
    // then emits s_load for all derived uniform loads.
    auto rflp = [](const void* p) -> const char* {
        u64 v = (u64)(uintptr_t)p;
        u32 lo = __builtin_amdgcn_readfirstlane((u32)v);
        u32 hi = __builtin_amdgcn_readfirstlane((u32)(v >> 32));
        return (const char*)(uintptr_t)(((u64)hi << 32) | lo);
    };
    const u32* lp = (const u32*)rflp(list + (size_t)row * 2048);
    const char* w1b = rflp(W1);
    const float* lutu = (const float*)rflp(lut);
    int cnt = __builtin_amdgcn_readfirstlane(ccnt[row]);   // multiple of 4
    u32 laneoff = (u32)j0 * 4u;                            // loop-invariant

    float a0[15], a1[15], a2[15], a3[15];
#pragma unroll
    for (int t = 0; t < 15; ++t) { a0[t] = 0.f; a1[t] = 0.f; a2[t] = 0.f; a3[t] = 0.f; }

#define ENT(S) {                                                       \
        u32 n_ = (S) & 15u;                                            \
        const float* br_ = lutu + (n_ << 4);        /* s_load x16 */   \
        float4 w_ = *(const float4*)(w1b + ((S) & ~15u) + laneoff);    \
        _Pragma("unroll")                                              \
        for (int t = 0; t < 15; ++t) {                                 \
            float b_ = br_[t];                      /* SGPR */         \
            a0[t] = __fmaf_rn(b_, w_.x, a0[t]);                        \
            a1[t] = __fmaf_rn(b_, w_.y, a1[t]);                        \
            a2[t] = __fmaf_rn(b_, w_.z, a2[t]);                        \
            a3[t] = __fmaf_rn(b_, w_.w, a3[t]);                        \
        }                                                              \
    }

    for (int i = 0; i < cnt; i += 4) {
        uint4 e = *(const uint4*)(lp + i);          // s_load_dwordx4
        ENT(e.x) ENT(e.y) ENT(e.z) ENT(e.w)
    }
#undef ENT

    // layer-1 recurrence per element (np rounding order) -> s1 bitmasks
    auto rec = [](const float* a) -> u16 {
        float syn = 0.f, mem = 0.f;
        u32 obits = 0;
#pragma unroll
        for (int t = 0; t < 15; ++t) {
            float ns = __fadd_rn(__fmul_rn(0.9f, syn), a[t]);
            float nm = __fadd_rn(__fmul_rn(0.85f, mem), ns);
            bool sp = nm > 1.0f;
            obits |= (sp ? 1u : 0u) << t;
            syn = ns;
            mem = sp ? 0.f : nm;
        }
        return (u16)obits;
    };
    u16 ob0 = rec(a0), ob1 = rec(a1), ob2 = rec(a2), ob3 = rec(a3);
    uint2 pk;
    pk.x = (u32)ob0 | ((u32)ob1 << 16);
    pk.y = (u32)ob2 | ((u32)ob3 << 16);
    *(uint2*)(s1b + (size_t)row * 2048 + j0) = pk;
}

// ---- K3: out = tanh(sum_t s1_t @ W2) (order-free reduction) ----
__global__ __launch_bounds__(256) void out_kernel(
    const u16* __restrict__ s1b, const float* __restrict__ W2,
    float* __restrict__ out) {
    __shared__ float P[4][15][8];
    int row = blockIdx.x;
    int tid = threadIdx.x, lane = tid & 63, wv = tid >> 6;
    const u16* srow = s1b + (size_t)row * 2048;
    union { uint4 v; u16 m[8]; } u;
    u.v = *(const uint4*)(srow + tid * 8);
#pragma unroll
    for (int t = 0; t < 15; ++t) {
        float a[8];
#pragma unroll
        for (int jj = 0; jj < 8; ++jj) a[jj] = 0.f;
#pragma unroll
        for (int kk = 0; kk < 8; ++kk) {
            const float* wr = W2 + (size_t)(tid * 8 + kk) * 8;
            if ((u.m[kk] >> t) & 1u) {
#pragma unroll
                for (int jj = 0; jj < 8; ++jj)
                    a[jj] = __fadd_rn(a[jj], wr[jj]);
            }
        }
#pragma unroll
        for (int jj = 0; jj < 8; ++jj) {
            float v = a[jj];
#pragma unroll
            for (int m = 1; m < 64; m <<= 1) v += __shfl_xor(v, m, 64);
            a[jj] = v;
        }
        if (lane == 0) {
#pragma unroll
            for (int jj = 0; jj < 8; ++jj) P[wv][t][jj] = a[jj];
        }
    }
    __syncthreads();
    if (tid < 8) {
        float m2 = 0.f;
#pragma unroll
        for (int t = 0; t < 15; ++t) {
            float s = __fadd_rn(__fadd_rn(P[0][t][tid], P[1][t][tid]),
                                __fadd_rn(P[2][t][tid], P[3][t][tid]));
            m2 = __fadd_rn(m2, s);
        }
        out[(size_t)row * 8 + tid] = tanhf(m2);
    }
}

extern "C" void kernel_launch(void* const* d_in, const int* in_sizes, int n_in,
                              void* d_out, int out_size, void* d_ws, size_t ws_size,
                              hipStream_t stream) {
    const float* inp = (const float*)d_in[0];
    const float* W0  = (const float*)d_in[1];
    const float* W1  = (const float*)d_in[2];
    const float* W2  = (const float*)d_in[3];
    float* out = (float*)d_out;
    char* ws = (char*)d_ws;

    u16*   s0bR = (u16*)(ws + 0);          // 16,777,216  [row][k] 15-bit masks
    u16*   s1b  = (u16*)(ws + 16777216);   // 16,777,216  [row][j] 15-bit masks
    u32*   list = (u32*)(ws + 33554432);   // 33,554,432  [row][2048] (k<<13|n)
    int*   ccnt = (int*)(ws + 67108864);   //     16,384  padded counts
    float* lut  = (float*)(ws + 67125248); //      1,024  16x16 b-LUT
    if (ws_size < 67126272) return;        // ~64 MB scratch

    h0_kernel<<<dim3(8, 128), 256, 0, stream>>>(inp, W0, s0bR);
    compact_kernel<<<1024, 256, 0, stream>>>(s0bR, list, ccnt, lut);
    h1_fused14<<<8192, 256, 0, stream>>>(W1, list, ccnt, lut, s1b);
    out_kernel<<<4096, 256, 0, stream>>>(s1b, W2, out);
}

// Round 19
// 5003.875 us; speedup vs baseline: 1.0144x; 1.0144x over previous
//
#include <hip/hip_runtime.h>
#include <math.h>

// TD3ActorDSNN — f32 class-faithful, fused, round 19.
// Exactness invariants (validated r4-r6, r9, r11-r18):
//  - per-element k-ascending single-accumulator f32 chains for h0 and h1;
//    skipping k with mask==0 is bit-identical; per-chain k-order fixed.
//  - b in {0,1}: fma(b,w,acc) EXACT; b=0 -> no-op; b=1 -> validated add.
//  - masks periodic (mem0 resets to exact 0): n = ctz+1; bit t = ((t+1)%n==0).
//  - recurrences: __fadd_rn(__fmul_rn(beta,state),h) (np mul-then-add).
//  - layer2/mem2: order-free (tanh input, tol 2e-2 >> 1e-6 noise).
// Codegen ledger:
//  SPILL: any branch/asm on the 60 live accs (r7/r8/r13/r15). r10/(256,8):
//    accs live in AGPRs (r16: VGPR=40 + ~64 AGPR, unified file) -> total
//    ~104 regs; forcing 8 waves/EU caps at 64 -> guaranteed spill. (256,4).
//  r14: dense per-t SALU selects saturate the CU-shared scalar pipe.
//  r18: pointer laundering via readfirstlane+inttoptr kills SMEM selection
//    AND forces 64-bit VALU address chains -> 2x regression. No rfl.
//  r17/spec: no packed-f32 rate advantage on gfx950. Floor = 60 fma/entry.
//  per-t lists (skip b=0): 8.3x W1 re-reads = 251 GB L2 -> ~8ms. Dead.
// Round-19: r16 body + 32-bit voffset addressing (SGPR kernel-arg base +
// u32 byte offset -> saddr-form global_load). Entry = k<<13 | n.

typedef unsigned int u32;
typedef unsigned short u16;
typedef unsigned long long u64;

// ---- K1: h0 = inputs @ W0 (f32 fma chain) + fused mem0 recurrence -> s0bR ----
__global__ __launch_bounds__(256) void h0_kernel(
    const float* __restrict__ in, const float* __restrict__ W0,
    u16* __restrict__ s0bR) {
    __shared__ float Ls[32 * 512];
    int tid = threadIdx.x;
    int j = blockIdx.x * 256 + tid;
    int r0 = blockIdx.y * 32;
#pragma unroll
    for (int i = 0; i < 64; ++i) {
        int e = i * 256 + tid;
        Ls[e] = in[(size_t)(r0 + (e >> 9)) * 512 + (e & 511)];
    }
    __syncthreads();
    float acc[32];
#pragma unroll
    for (int r = 0; r < 32; ++r) acc[r] = 0.f;
    for (int k = 0; k < 512; ++k) {
        float w = W0[(size_t)k * 2048 + j];
#pragma unroll
        for (int r = 0; r < 32; ++r)
            acc[r] = __fmaf_rn(Ls[r * 512 + k], w, acc[r]);
    }
#pragma unroll
    for (int r = 0; r < 32; ++r) {
        float h = acc[r], mem = 0.f;
        u32 bits = 0;
#pragma unroll
        for (int t = 0; t < 15; ++t) {
            float nm = __fadd_rn(__fmul_rn(0.85f, mem), h);  // np: mul, then add
            bool sp = nm > 1.0f;
            bits |= (sp ? 1u : 0u) << t;
            mem = sp ? 0.f : nm;
        }
        s0bR[(size_t)(r0 + r) * 2048 + j] = (u16)bits;
    }
}

// ---- K1b: active-k compaction (k-ascending) + 16x16 b-LUT ----
// entry = k<<13 | n (byte offset of W1 row | period). pad x2 with 0
// (n=0 -> lut row 0 zeros -> exact no-op; w load from row 0 harmless).
__global__ __launch_bounds__(256) void compact_kernel(
    const u16* __restrict__ s0bR, u32* __restrict__ list,
    int* __restrict__ ccnt, float* __restrict__ lut) {
    int wv = threadIdx.x >> 6, lane = threadIdx.x & 63;
    if (blockIdx.x == 0) {    // lut[n][t] = ((t+1)%n==0), row 0 = zeros
        int n = threadIdx.x >> 4, t = threadIdx.x & 15;
        lut[threadIdx.x] = (n >= 1 && t < 15 && ((t + 1) % n == 0)) ? 1.0f : 0.0f;
    }
    int row = blockIdx.x * 4 + wv;
    const u16* mrow = s0bR + (size_t)row * 2048;
    u32* lrow = list + (size_t)row * 2048;
    int base = 0;
    for (int c = 0; c < 32; ++c) {
        int k = c * 64 + lane;
        u32 m = mrow[k];
        bool act = m != 0u;
        u64 b = __ballot(act ? 1 : 0);
        int pre = __popcll(b & ((1ull << lane) - 1ull));
        if (act) lrow[base + pre] =
            ((u32)k << 13) | (u32)(__builtin_ctz(m | 0x10000u) + 1);
        base += __popcll(b);
    }
    int padded = (base + 1) & ~1;
    if (lane < (padded - base)) lrow[base + lane] = 0u;
    if (lane == 0) ccnt[row] = padded;
}

// ---- K2: FUSED h1 (15 steps) over ACTIVE k only + recurrence -> s1b ----
// Wave: 1 row x 256 cols (lane: 4 cols). Block: 4 rows. grid 8192:
// jb = id&7 (XCD-affine W1 slice), rblk = id>>3.
// All loads = SGPR kernel-arg base + 32-bit voffset (saddr form).
__global__ __launch_bounds__(256, 4) void h1_fused15(
    const char* __restrict__ W1c, const char* __restrict__ listc,
    const int* __restrict__ ccnt, const char* __restrict__ lutc,
    u16* __restrict__ s1b) {
    int id = blockIdx.x;
    int jb = id & 7, rblk = id >> 3;
    int lane = threadIdx.x & 63, wv = threadIdx.x >> 6;
    int row = rblk * 4 + wv;
    int j0 = jb * 256 + lane * 4;
    u32 vj = (u32)j0 * 4u;                   // per-lane, loop-invariant
    u32 lbase = (u32)row * 8192u;            // list byte base for this row
    int cnt = ccnt[row];                     // padded to multiple of 2

    float a0[15], a1[15], a2[15], a3[15];
#pragma unroll
    for (int t = 0; t < 15; ++t) { a0[t] = 0.f; a1[t] = 0.f; a2[t] = 0.f; a3[t] = 0.f; }

#define FMA4(BT, T, W)                                   \
    a0[T] = __fmaf_rn(BT, W.x, a0[T]);                   \
    a1[T] = __fmaf_rn(BT, W.y, a1[T]);                   \
    a2[T] = __fmaf_rn(BT, W.z, a2[T]);                   \
    a3[T] = __fmaf_rn(BT, W.w, a3[T]);

#define BODY(W, BA, BB, BC, BD)                          \
    FMA4(BA.x, 0, W) FMA4(BA.y, 1, W) FMA4(BA.z, 2, W) FMA4(BA.w, 3, W) \
    FMA4(BB.x, 4, W) FMA4(BB.y, 5, W) FMA4(BB.z, 6, W) FMA4(BB.w, 7, W) \
    FMA4(BC.x, 8, W) FMA4(BC.y, 9, W) FMA4(BC.z,10, W) FMA4(BC.w,11, W) \
    FMA4(BD.x,12, W) FMA4(BD.y,13, W) FMA4(BD.z,14, W)

    for (int i = 0; i < cnt; i += 2) {
        // list: 2 entries via 32-bit voffset off SGPR base
        uint2 e = *(const uint2*)(listc + (lbase + (u32)i * 4u));
        u32 w0off = (e.x & ~15u) + vj;       // k<<13 | n -> row byte + col byte
        u32 w1off = (e.y & ~15u) + vj;
        u32 b0off = (e.x & 15u) << 6;        // 64B LUT rows
        u32 b1off = (e.y & 15u) << 6;
        // all loads issued up front (latency overlap), saddr + u32 voffset
        float4 w0 = *(const float4*)(W1c + w0off);
        float4 w1 = *(const float4*)(W1c + w1off);
        float4 p0 = *(const float4*)(lutc + b0off);
        float4 p1 = *(const float4*)(lutc + b0off + 16);
        float4 p2 = *(const float4*)(lutc + b0off + 32);
        float4 p3 = *(const float4*)(lutc + b0off + 48);
        float4 q0 = *(const float4*)(lutc + b1off);
        float4 q1 = *(const float4*)(lutc + b1off + 16);
        float4 q2 = *(const float4*)(lutc + b1off + 32);
        float4 q3 = *(const float4*)(lutc + b1off + 48);
        BODY(w0, p0, p1, p2, p3)
        BODY(w1, q0, q1, q2, q3)
    }
#undef BODY
#undef FMA4

    // layer-1 recurrence per element (np rounding order) -> s1 bitmasks
    auto rec = [](const float* a) -> u16 {
        float syn = 0.f, mem = 0.f;
        u32 obits = 0;
#pragma unroll
        for (int t = 0; t < 15; ++t) {
            float ns = __fadd_rn(__fmul_rn(0.9f, syn), a[t]);
            float nm = __fadd_rn(__fmul_rn(0.85f, mem), ns);
            bool sp = nm > 1.0f;
            obits |= (sp ? 1u : 0u) << t;
            syn = ns;
            mem = sp ? 0.f : nm;
        }
        return (u16)obits;
    };
    u16 ob0 = rec(a0), ob1 = rec(a1), ob2 = rec(a2), ob3 = rec(a3);
    uint2 pk;
    pk.x = (u32)ob0 | ((u32)ob1 << 16);
    pk.y = (u32)ob2 | ((u32)ob3 << 16);
    *(uint2*)(s1b + (size_t)row * 2048 + j0) = pk;
}

// ---- K3: out = tanh(sum_t s1_t @ W2) (order-free reduction) ----
__global__ __launch_bounds__(256) void out_kernel(
    const u16* __restrict__ s1b, const float* __restrict__ W2,
    float* __restrict__ out) {
    __shared__ float P[4][15][8];
    int row = blockIdx.x;
    int tid = threadIdx.x, lane = tid & 63, wv = tid >> 6;
    const u16* srow = s1b + (size_t)row * 2048;
    union { uint4 v; u16 m[8]; } u;
    u.v = *(const uint4*)(srow + tid * 8);
#pragma unroll
    for (int t = 0; t < 15; ++t) {
        float a[8];
#pragma unroll
        for (int jj = 0; jj < 8; ++jj) a[jj] = 0.f;
#pragma unroll
        for (int kk = 0; kk < 8; ++kk) {
            const float* wr = W2 + (size_t)(tid * 8 + kk) * 8;
            if ((u.m[kk] >> t) & 1u) {
#pragma unroll
                for (int jj = 0; jj < 8; ++jj)
                    a[jj] = __fadd_rn(a[jj], wr[jj]);
            }
        }
#pragma unroll
        for (int jj = 0; jj < 8; ++jj) {
            float v = a[jj];
#pragma unroll
            for (int m = 1; m < 64; m <<= 1) v += __shfl_xor(v, m, 64);
            a[jj] = v;
        }
        if (lane == 0) {
#pragma unroll
            for (int jj = 0; jj < 8; ++jj) P[wv][t][jj] = a[jj];
        }
    }
    __syncthreads();
    if (tid < 8) {
        float m2 = 0.f;
#pragma unroll
        for (int t = 0; t < 15; ++t) {
            float s = __fadd_rn(__fadd_rn(P[0][t][tid], P[1][t][tid]),
                                __fadd_rn(P[2][t][tid], P[3][t][tid]));
            m2 = __fadd_rn(m2, s);
        }
        out[(size_t)row * 8 + tid] = tanhf(m2);
    }
}

extern "C" void kernel_launch(void* const* d_in, const int* in_sizes, int n_in,
                              void* d_out, int out_size, void* d_ws, size_t ws_size,
                              hipStream_t stream) {
    const float* inp = (const float*)d_in[0];
    const float* W0  = (const float*)d_in[1];
    const float* W1  = (const float*)d_in[2];
    const float* W2  = (const float*)d_in[3];
    float* out = (float*)d_out;
    char* ws = (char*)d_ws;

    u16*   s0bR = (u16*)(ws + 0);          // 16,777,216  [row][k] 15-bit masks
    u16*   s1b  = (u16*)(ws + 16777216);   // 16,777,216  [row][j] 15-bit masks
    u32*   list = (u32*)(ws + 33554432);   // 33,554,432  [row][2048] (k<<13|n)
    int*   ccnt = (int*)(ws + 67108864);   //     16,384  padded counts
    float* lut  = (float*)(ws + 67125248); //      1,024  16x16 b-LUT
    if (ws_size < 67126272) return;        // ~64 MB scratch

    h0_kernel<<<dim3(8, 128), 256, 0, stream>>>(inp, W0, s0bR);
    compact_kernel<<<1024, 256, 0, stream>>>(s0bR, list, ccnt, lut);
    h1_fused15<<<8192, 256, 0, stream>>>((const char*)W1, (const char*)list,
                                         ccnt, (const char*)lut, s1b);
    out_kernel<<<4096, 256, 0, stream>>>(s1b, W2, out);
}

// Round 20
// 2644.206 us; speedup vs baseline: 1.9196x; 1.8924x over previous
//
#include <hip/hip_runtime.h>
#include <math.h>

// TD3ActorDSNN — f32 class-faithful, fused, round 20 (revert to r16 optimum).
// Exactness invariants (validated r4-r6, r9, r11-r19):
//  - per-element k-ascending single-accumulator f32 chains for h0 and h1;
//    skipping k with mask==0 is bit-identical; order never changes.
//  - b in {0,1}: fma(b,w,acc) EXACT (b=1 -> RN(acc+w) == validated add;
//    b=0 -> acc unchanged; acc never -0 in a +0-seeded add chain).
//  - masks are PERIODIC (mem0 resets to exact 0): n = ctz(mask)+1; bit t set
//    iff (t+1)%n==0. Validated by r8's pass.
//  - recurrences: __fadd_rn(__fmul_rn(beta,state),h) (np mul-then-add).
//  - layer2/mem2: order-free (tanh input, tol 2e-2 >> 1e-6 noise).
// Final codegen ledger:
//  SPILL: any branch/asm on the 60 live accs (r7/r8/r13/r15); launch_bounds
//    (,8) reg cap (r10). SAFE: single-BB portable body at (256,4).
//  r14: dense per-t SALU selects saturate the CU-shared scalar pipe.
//  r17: v_pk_fma_f32 has NO rate advantage on gfx950 (157.3 TF peak equals
//    scalar SIMD-32 fma rate). r18/r19: pointer laundering / manual voffset
//    DESTROY the uniformity r16's codegen found on its own (SGPR 80 -> 32).
//  Per-t compacted lists: 8.3x W1 re-reads = 251 GB L2 ~ 8 ms. Dead.
// r16 profile: 2.65 ms, VALUBusy 83%, VGPR 40 (+accs in AGPR), SGPR 80
// (b-rows s_loaded), WRITE 16 MB, ~83 VALU/entry vs 60 algorithmic floor.

typedef unsigned int u32;
typedef unsigned short u16;
typedef unsigned long long u64;

// ---- K1: h0 = inputs @ W0 (f32 fma chain) + fused mem0 recurrence -> s0bR ----
__global__ __launch_bounds__(256) void h0_kernel(
    const float* __restrict__ in, const float* __restrict__ W0,
    u16* __restrict__ s0bR) {
    __shared__ float Ls[32 * 512];
    int tid = threadIdx.x;
    int j = blockIdx.x * 256 + tid;
    int r0 = blockIdx.y * 32;
#pragma unroll
    for (int i = 0; i < 64; ++i) {
        int e = i * 256 + tid;
        Ls[e] = in[(size_t)(r0 + (e >> 9)) * 512 + (e & 511)];
    }
    __syncthreads();
    float acc[32];
#pragma unroll
    for (int r = 0; r < 32; ++r) acc[r] = 0.f;
    for (int k = 0; k < 512; ++k) {
        float w = W0[(size_t)k * 2048 + j];
#pragma unroll
        for (int r = 0; r < 32; ++r)
            acc[r] = __fmaf_rn(Ls[r * 512 + k], w, acc[r]);
    }
#pragma unroll
    for (int r = 0; r < 32; ++r) {
        float h = acc[r], mem = 0.f;
        u32 bits = 0;
#pragma unroll
        for (int t = 0; t < 15; ++t) {
            float nm = __fadd_rn(__fmul_rn(0.85f, mem), h);  // np: mul, then add
            bool sp = nm > 1.0f;
            bits |= (sp ? 1u : 0u) << t;
            mem = sp ? 0.f : nm;
        }
        s0bR[(size_t)(r0 + r) * 2048 + j] = (u16)bits;
    }
}

// ---- K1b: active-k compaction (k-ascending) + b-LUT init ----
// entry = k<<16 | n, n = ctz(mask)+1 (periodic masks, r8-validated).
__global__ __launch_bounds__(256) void compact_kernel(
    const u16* __restrict__ s0bR, u32* __restrict__ list,
    int* __restrict__ ccnt, float* __restrict__ lut) {
    int wv = threadIdx.x >> 6, lane = threadIdx.x & 63;
    if (blockIdx.x == 0) {    // fill 16x16 LUT: lut[n][t] = ((t+1)%n==0)
        int n = threadIdx.x >> 4, t = threadIdx.x & 15;
        lut[threadIdx.x] = (n >= 1 && t < 15 && ((t + 1) % n == 0)) ? 1.0f : 0.0f;
    }
    int row = blockIdx.x * 4 + wv;
    const u16* mrow = s0bR + (size_t)row * 2048;
    u32* lrow = list + (size_t)row * 2048;
    int base = 0;
    for (int c = 0; c < 32; ++c) {
        int k = c * 64 + lane;
        u32 m = mrow[k];
        bool act = m != 0u;
        u64 b = __ballot(act ? 1 : 0);
        int pre = __popcll(b & ((1ull << lane) - 1ull));
        if (act) lrow[base + pre] = ((u32)k << 16) | (u32)(__builtin_ctz(m | 0x10000u) + 1);
        base += __popcll(b);
    }
    int padded = (base + 1) & ~1;
    if (lane < (padded - base)) lrow[base + lane] = 0u;   // n=0 -> lut zeros
    if (lane == 0) ccnt[row] = padded;
}

// ---- K2: FUSED h1 (15 steps) over ACTIVE k only + recurrence -> s1b ----
// Wave: 1 row x 256 cols (lane: 4 cols). Block: 4 rows. grid 8192:
// jb = id&7 (XCD-affine W1 slice), rblk = id>>3.
// Single straight-line body; b via broadcast LUT loads; 60 fma/entry.
__global__ __launch_bounds__(256, 4) void h1_fused12(
    const float* __restrict__ W1, const u32* __restrict__ list,
    const int* __restrict__ ccnt, const float* __restrict__ lut,
    u16* __restrict__ s1b) {
    int id = blockIdx.x;
    int jb = id & 7, rblk = id >> 3;
    int lane = threadIdx.x & 63, wv = threadIdx.x >> 6;
    int row = rblk * 4 + wv;
    int j0 = jb * 256 + lane * 4;
    const float* wp = W1 + j0;
    const u32* lp = list + (size_t)row * 2048;
    int cnt = ccnt[row];                      // padded to multiple of 2

    float a0[15], a1[15], a2[15], a3[15];
#pragma unroll
    for (int t = 0; t < 15; ++t) { a0[t] = 0.f; a1[t] = 0.f; a2[t] = 0.f; a3[t] = 0.f; }

#define FMA4(BT, T, W)                                   \
    a0[T] = __fmaf_rn(BT, W.x, a0[T]);                   \
    a1[T] = __fmaf_rn(BT, W.y, a1[T]);                   \
    a2[T] = __fmaf_rn(BT, W.z, a2[T]);                   \
    a3[T] = __fmaf_rn(BT, W.w, a3[T]);

#define BODY(W, BA, BB, BC, BD)                          \
    FMA4(BA.x, 0, W) FMA4(BA.y, 1, W) FMA4(BA.z, 2, W) FMA4(BA.w, 3, W) \
    FMA4(BB.x, 4, W) FMA4(BB.y, 5, W) FMA4(BB.z, 6, W) FMA4(BB.w, 7, W) \
    FMA4(BC.x, 8, W) FMA4(BC.y, 9, W) FMA4(BC.z,10, W) FMA4(BC.w,11, W) \
    FMA4(BD.x,12, W) FMA4(BD.y,13, W) FMA4(BD.z,14, W)

    for (int i = 0; i < cnt; i += 2) {
        uint2 e = *(const uint2*)(lp + i);    // 2 entries, wave-uniform addr
        u32 s0 = __builtin_amdgcn_readfirstlane(e.x);
        u32 s1 = __builtin_amdgcn_readfirstlane(e.y);
        // w loads (L2) issued up front for latency overlap
        float4 w0 = *(const float4*)(wp + ((size_t)(s0 >> 16) << 11));
        float4 w1 = *(const float4*)(wp + ((size_t)(s1 >> 16) << 11));
        // b vectors: broadcast loads from 1KB L1-hot LUT (uniform -> s_load)
        const float4* bp0 = (const float4*)(lut + ((s0 & 15u) << 4));
        const float4* bp1 = (const float4*)(lut + ((s1 & 15u) << 4));
        float4 ba0 = bp0[0], bb0 = bp0[1], bc0 = bp0[2], bd0 = bp0[3];
        float4 ba1 = bp1[0], bb1 = bp1[1], bc1 = bp1[2], bd1 = bp1[3];
        BODY(w0, ba0, bb0, bc0, bd0)
        BODY(w1, ba1, bb1, bc1, bd1)
    }
#undef BODY
#undef FMA4

    // layer-1 recurrence per element (np rounding order) -> s1 bitmasks
    auto rec = [](const float* a) -> u16 {
        float syn = 0.f, mem = 0.f;
        u32 obits = 0;
#pragma unroll
        for (int t = 0; t < 15; ++t) {
            float ns = __fadd_rn(__fmul_rn(0.9f, syn), a[t]);
            float nm = __fadd_rn(__fmul_rn(0.85f, mem), ns);
            bool sp = nm > 1.0f;
            obits |= (sp ? 1u : 0u) << t;
            syn = ns;
            mem = sp ? 0.f : nm;
        }
        return (u16)obits;
    };
    u16 ob0 = rec(a0), ob1 = rec(a1), ob2 = rec(a2), ob3 = rec(a3);
    uint2 pk;
    pk.x = (u32)ob0 | ((u32)ob1 << 16);
    pk.y = (u32)ob2 | ((u32)ob3 << 16);
    *(uint2*)(s1b + (size_t)row * 2048 + j0) = pk;
}

// ---- K3: out = tanh(sum_t s1_t @ W2) (order-free reduction) ----
__global__ __launch_bounds__(256) void out_kernel(
    const u16* __restrict__ s1b, const float* __restrict__ W2,
    float* __restrict__ out) {
    __shared__ float P[4][15][8];
    int row = blockIdx.x;
    int tid = threadIdx.x, lane = tid & 63, wv = tid >> 6;
    const u16* srow = s1b + (size_t)row * 2048;
    union { uint4 v; u16 m[8]; } u;
    u.v = *(const uint4*)(srow + tid * 8);
#pragma unroll
    for (int t = 0; t < 15; ++t) {
        float a[8];
#pragma unroll
        for (int jj = 0; jj < 8; ++jj) a[jj] = 0.f;
#pragma unroll
        for (int kk = 0; kk < 8; ++kk) {
            const float* wr = W2 + (size_t)(tid * 8 + kk) * 8;
            if ((u.m[kk] >> t) & 1u) {
#pragma unroll
                for (int jj = 0; jj < 8; ++jj)
                    a[jj] = __fadd_rn(a[jj], wr[jj]);
            }
        }
#pragma unroll
        for (int jj = 0; jj < 8; ++jj) {
            float v = a[jj];
#pragma unroll
            for (int m = 1; m < 64; m <<= 1) v += __shfl_xor(v, m, 64);
            a[jj] = v;
        }
        if (lane == 0) {
#pragma unroll
            for (int jj = 0; jj < 8; ++jj) P[wv][t][jj] = a[jj];
        }
    }
    __syncthreads();
    if (tid < 8) {
        float m2 = 0.f;
#pragma unroll
        for (int t = 0; t < 15; ++t) {
            float s = __fadd_rn(__fadd_rn(P[0][t][tid], P[1][t][tid]),
                                __fadd_rn(P[2][t][tid], P[3][t][tid]));
            m2 = __fadd_rn(m2, s);
        }
        out[(size_t)row * 8 + tid] = tanhf(m2);
    }
}

extern "C" void kernel_launch(void* const* d_in, const int* in_sizes, int n_in,
                              void* d_out, int out_size, void* d_ws, size_t ws_size,
                              hipStream_t stream) {
    const float* inp = (const float*)d_in[0];
    const float* W0  = (const float*)d_in[1];
    const float* W1  = (const float*)d_in[2];
    const float* W2  = (const float*)d_in[3];
    float* out = (float*)d_out;
    char* ws = (char*)d_ws;

    u16*   s0bR = (u16*)(ws + 0);          // 16,777,216  [row][k] 15-bit masks
    u16*   s1b  = (u16*)(ws + 16777216);   // 16,777,216  [row][j] 15-bit masks
    u32*   list = (u32*)(ws + 33554432);   // 33,554,432  [row][2048] (k<<16|n)
    int*   ccnt = (int*)(ws + 67108864);   //     16,384  padded counts
    float* lut  = (float*)(ws + 67125248); //      1,024  16x16 b-LUT
    if (ws_size < 67126272) return;        // ~64 MB scratch

    h0_kernel<<<dim3(8, 128), 256, 0, stream>>>(inp, W0, s0bR);
    compact_kernel<<<1024, 256, 0, stream>>>(s0bR, list, ccnt, lut);
    h1_fused12<<<8192, 256, 0, stream>>>(W1, list, ccnt, lut, s1b);
    out_kernel<<<4096, 256, 0, stream>>>(s1b, W2, out);
}